// Round 1
// baseline (316.439 us; speedup 1.0000x reference)
//
#include <hip/hip_runtime.h>
#include <hip/hip_bf16.h>
#include <math.h>

// Problem constants (from reference): BSZ=64, BEAM=8, VOCAB=50257, STEP=5
#define BSZ   64
#define BEAM  8
#define VOCAB 50257
#define NSTEP 5
#define K     16
#define DIVERSITY_RATE 0.5f

// ---- order-preserving float<->uint transforms (finite values) ----
__device__ __forceinline__ unsigned f2s(float f) {
    unsigned u = __float_as_uint(f);
    return (u & 0x80000000u) ? ~u : (u | 0x80000000u);
}
__device__ __forceinline__ float s2f(unsigned s) {
    unsigned u = (s & 0x80000000u) ? (s ^ 0x80000000u) : ~s;
    return __uint_as_float(u);
}

// wave(64)-wide max reduction of a u64 key via two 32-bit shuffles per step
__device__ __forceinline__ unsigned long long wmax64(unsigned long long k) {
#pragma unroll
    for (int off = 32; off > 0; off >>= 1) {
        unsigned lo = __shfl_xor((unsigned)k, off, 64);
        unsigned hi = __shfl_xor((unsigned)(k >> 32), off, 64);
        unsigned long long o = ((unsigned long long)hi << 32) | lo;
        if (o > k) k = o;
    }
    return k;
}

// Phase 1: per (bsz*beam) row, top-16 of lprobs[row,:] + bias, with
// lower-vocab-index tie-break (JAX top_k stability). Sorted results -> ws.
__global__ __launch_bounds__(256) void topk_rows(
    const float* __restrict__ lprobs, const float* __restrict__ scores,
    const int* __restrict__ step_ptr, float* __restrict__ topv,
    int* __restrict__ topi)
{
    const int row  = blockIdx.x;        // b*BEAM + j
    const int tid  = threadIdx.x;       // 0..255
    const int lane = tid & 63;
    const int wave = tid >> 6;          // 0..3

    const int step = *step_ptr;
    const float add = (step > 0) ? scores[row * NSTEP + (step - 1)] : 0.0f;

    const float* rowp = lprobs + (size_t)row * VOCAB;
    const float4* rowp4 = (const float4*)rowp;
    const int n4 = VOCAB / 4;           // 12564 (remainder: 1 element)

    // register-resident sorted (desc) top-16
    float vals[K];
    int   idxs[K];
#pragma unroll
    for (int i = 0; i < K; ++i) { vals[i] = -INFINITY; idxs[i] = 0x7FFFFFFF; }

#define INSERT1(v, id)                                                        \
    do {                                                                      \
        float _v = (v);                                                       \
        if (_v > vals[K - 1]) {                                               \
            _Pragma("unroll")                                                 \
            for (int _t = K - 1; _t > 0; --_t)                                \
                if (vals[_t - 1] < _v) { vals[_t] = vals[_t - 1];             \
                                         idxs[_t] = idxs[_t - 1]; }           \
            bool _done = false;                                               \
            _Pragma("unroll")                                                 \
            for (int _t = 0; _t < K; ++_t) {                                  \
                bool _pl = !_done && (_t == 0 || vals[_t - 1] >= _v)          \
                                  && (vals[_t] < _v);                         \
                if (_pl) { vals[_t] = _v; idxs[_t] = (id); _done = true; }    \
            }                                                                 \
        }                                                                     \
    } while (0)

#define PROC4(f4, i4)                                                         \
    do {                                                                      \
        INSERT1((f4).x + add, 4 * (i4) + 0);                                  \
        INSERT1((f4).y + add, 4 * (i4) + 1);                                  \
        INSERT1((f4).z + add, 4 * (i4) + 2);                                  \
        INSERT1((f4).w + add, 4 * (i4) + 3);                                  \
    } while (0)

    int i = tid;
    for (; i + 768 < n4; i += 1024) {           // 4x unroll: loads up front
        float4 a = rowp4[i];
        float4 b = rowp4[i + 256];
        float4 c = rowp4[i + 512];
        float4 d = rowp4[i + 768];
        PROC4(a, i); PROC4(b, i + 256); PROC4(c, i + 512); PROC4(d, i + 768);
    }
    for (; i < n4; i += 256) {
        float4 a = rowp4[i];
        PROC4(a, i);
    }
    if (tid == 0) {                              // tail element 50256
        INSERT1(rowp[VOCAB - 1] + add, VOCAB - 1);
    }

    // ---- per-wave iterative extraction: 16 rounds of wave argmax ----
    // key = sortable(value)<<32 | ~idx  (ties -> lower vocab idx wins; unique)
    __shared__ unsigned long long lds[4 * K];
#pragma unroll 1
    for (int it = 0; it < K; ++it) {
        unsigned long long key =
            ((unsigned long long)f2s(vals[0]) << 32) | (unsigned)(~idxs[0]);
        unsigned long long m = wmax64(key);
        if (key == m) {                           // owner: pop head
#pragma unroll
            for (int t = 0; t < K - 1; ++t) { vals[t] = vals[t + 1];
                                              idxs[t] = idxs[t + 1]; }
            vals[K - 1] = -INFINITY; idxs[K - 1] = 0x7FFFFFFF;
        }
        if (lane == 0) lds[wave * K + it] = m;
    }
    __syncthreads();

    // ---- wave 0 merges the 4 sorted wave-lists (64 candidates) ----
    if (tid < 64) {
        unsigned long long cand = lds[tid];
        unsigned long long mine = 0;
#pragma unroll 1
        for (int it = 0; it < K; ++it) {
            unsigned long long m = wmax64(cand);
            if (lane == it) mine = m;
            if (cand == m) cand = 0;              // kill extracted candidate
        }
        if (lane < K) {
            unsigned sv = (unsigned)(mine >> 32);
            topv[row * K + lane] = s2f(sv);
            topi[row * K + lane] = (int)(~(unsigned)mine);
        }
    }
}

// Phase 2: per bsz, top-16 of the 128 sibling-penalized candidates with
// flattened-position tie-break; write scores / vocab indices / beams.
__global__ __launch_bounds__(64) void finalize(
    const float* __restrict__ topv, const int* __restrict__ topi,
    const int* __restrict__ step_ptr, float* __restrict__ out)
{
    const int b    = blockIdx.x;     // 0..63
    const int lane = threadIdx.x;    // 0..63
    const int step = *step_ptr;

    float* out_scores = out;
    float* out_idx    = out + BSZ * K;
    float* out_beam   = out + 2 * BSZ * K;

    if (step == 0) {
        // reference: top_k(lprobs[:,0,:]) -> i%vocab=i, i//vocab=0
        if (lane < K) {
            out_scores[b * K + lane] = topv[(b * BEAM + 0) * K + lane];
            out_idx[b * K + lane]    = (float)topi[(b * BEAM + 0) * K + lane];
            out_beam[b * K + lane]   = 0.0f;
        }
        return;
    }

    // candidates c = lane and lane+64; key low32 = 127-c (lower c wins ties)
    unsigned long long ka, kb;
    {
        int c = lane, j = c >> 4, r = c & 15;
        float s = topv[(b * BEAM + j) * K + r] - (float)(r + 1) * DIVERSITY_RATE;
        ka = ((unsigned long long)f2s(s) << 32) | (unsigned)(127 - c);
    }
    {
        int c = lane + 64, j = c >> 4, r = c & 15;
        float s = topv[(b * BEAM + j) * K + r] - (float)(r + 1) * DIVERSITY_RATE;
        kb = ((unsigned long long)f2s(s) << 32) | (unsigned)(127 - c);
    }

    unsigned long long mine = 0;
#pragma unroll 1
    for (int it = 0; it < K; ++it) {
        unsigned long long k = (ka > kb) ? ka : kb;
        unsigned long long m = wmax64(k);
        if (lane == it) mine = m;
        if (ka == m) ka = 0; else if (kb == m) kb = 0;
    }

    if (lane < K) {
        unsigned sv = (unsigned)(mine >> 32);
        int c = 127 - (int)(mine & 0xFFFFFFFFull);
        int j = c >> 4, r = c & 15;
        out_scores[b * K + lane] = s2f(sv);
        out_idx[b * K + lane]    = (float)topi[(b * BEAM + j) * K + r];
        out_beam[b * K + lane]   = (float)j;
    }
}

extern "C" void kernel_launch(void* const* d_in, const int* in_sizes, int n_in,
                              void* d_out, int out_size, void* d_ws, size_t ws_size,
                              hipStream_t stream) {
    const float* lprobs = (const float*)d_in[0];
    const float* scores = (const float*)d_in[1];
    const int*   step   = (const int*)d_in[2];

    float* topv = (float*)d_ws;                                   // 512*16 f32
    int*   topi = (int*)((char*)d_ws + (size_t)BSZ * BEAM * K * sizeof(float));

    topk_rows<<<BSZ * BEAM, 256, 0, stream>>>(lprobs, scores, step, topv, topi);
    finalize<<<BSZ, 64, 0, stream>>>(topv, topi, step, (float*)d_out);
}

// Round 2
// 197.632 us; speedup vs baseline: 1.6012x; 1.6012x over previous
//
#include <hip/hip_runtime.h>
#include <math.h>

// Problem constants: BSZ=64, BEAM=8, VOCAB=50257, STEP=5
#define BSZ   64
#define BEAM  8
#define VOCAB 50257
#define NSTEP 5
#define K     16
#define DIV_RATE 0.5f
#define SPLIT 8
#define N4    (VOCAB / 4)                  // 12564 float4s (+1 tail elem)
#define F4SEG ((N4 + SPLIT - 1) / SPLIT)   // 1571 float4 per segment
#define CAP   512                          // candidate buffer (proof bound: 448)

typedef unsigned long long u64;
typedef unsigned u32;

// order-preserving float<->uint (finite values)
__device__ __forceinline__ u32 f2s(float f) {
    u32 u = __float_as_uint(f);
    return (u & 0x80000000u) ? ~u : (u | 0x80000000u);
}
__device__ __forceinline__ float s2f(u32 s) {
    u32 u = (s & 0x80000000u) ? (s ^ 0x80000000u) : ~s;
    return __uint_as_float(u);
}

// wave(64)-wide max of a u64 key
__device__ __forceinline__ u64 wmax64(u64 k) {
#pragma unroll
    for (int off = 32; off > 0; off >>= 1) {
        u32 lo = __shfl_xor((u32)k, off, 64);
        u32 hi = __shfl_xor((u32)(k >> 32), off, 64);
        u64 o = ((u64)hi << 32) | lo;
        if (o > k) k = o;
    }
    return k;
}

// Phase 1: per (row, segment): exact top-16 via threshold-select.
//   T = 16th largest of the 256 per-thread maxima (subset property => T <= x16,
//   and elements >= T live in <= 16 threads => <= 16*28 = 448 candidates).
// Emits 16 sorted keys (f2s(value)<<32 | ~vocab_idx) per segment. Bias is a
// per-row constant => applied later (top-k invariant under uniform shift).
__global__ __launch_bounds__(256) void topk_seg(
    const float* __restrict__ lprobs, u64* __restrict__ segk)
{
    const int tid  = threadIdx.x;
    const int lane = tid & 63;
    const int wave = tid >> 6;
    const int seg  = blockIdx.x;     // 0..7
    const int row  = blockIdx.y;     // 0..511

    const int s0 = seg * F4SEG;
    const int s1 = min(N4, s0 + F4SEG);
    const float4* rp4 = (const float4*)(lprobs + (size_t)row * VOCAB);

    // ---- pass 1: load segment into registers, per-thread max ----
    float4 d[7];
#pragma unroll
    for (int k = 0; k < 7; ++k) {
        int p = s0 + k * 256 + tid;
        if (p < s1) d[k] = rp4[p];
        else        d[k] = make_float4(-INFINITY, -INFINITY, -INFINITY, -INFINITY);
    }
    float extra = -INFINITY;                       // vocab tail element 50256
    if (seg == SPLIT - 1 && tid == 0) extra = ((const float*)rp4)[VOCAB - 1];

    float m = extra;
#pragma unroll
    for (int k = 0; k < 7; ++k)
        m = fmaxf(m, fmaxf(fmaxf(d[k].x, d[k].y), fmaxf(d[k].z, d[k].w)));

    __shared__ float smax[256];
    __shared__ u64   sbuf[CAP];
    __shared__ u64   wlist[4 * K];
    __shared__ int   scnt;
    __shared__ float sT;
    smax[tid] = m;
    sbuf[tid] = 0; sbuf[tid + 256] = 0;
    if (tid == 0) scnt = 0;
    __syncthreads();

    // ---- threshold: wave 0 extracts 16th largest of the 256 maxima ----
    if (wave == 0) {
        u64 k0 = ((u64)f2s(smax[lane      ]) << 32) | (u32)lane;
        u64 k1 = ((u64)f2s(smax[lane +  64]) << 32) | (u32)(lane + 64);
        u64 k2 = ((u64)f2s(smax[lane + 128]) << 32) | (u32)(lane + 128);
        u64 k3 = ((u64)f2s(smax[lane + 192]) << 32) | (u32)(lane + 192);
        u64 last = 0;
#pragma unroll 1
        for (int it = 0; it < K; ++it) {
            u64 la = k0 > k1 ? k0 : k1;
            u64 lb = k2 > k3 ? k2 : k3;
            u64 mm = wmax64(la > lb ? la : lb);
            if (k0 == mm) k0 = 0; else if (k1 == mm) k1 = 0;
            else if (k2 == mm) k2 = 0; else if (k3 == mm) k3 = 0;
            last = mm;
        }
        if (lane == 0) sT = s2f((u32)(last >> 32));
    }
    __syncthreads();
    const float T = sT;

    // ---- pass 3: collect candidates >= T from registers ----
#pragma unroll
    for (int k = 0; k < 7; ++k) {
        int base4 = 4 * (s0 + k * 256 + tid);
        if (d[k].x >= T) { int p = atomicAdd(&scnt, 1); if (p < CAP) sbuf[p] = ((u64)f2s(d[k].x) << 32) | (u32)~(u32)(base4 + 0); }
        if (d[k].y >= T) { int p = atomicAdd(&scnt, 1); if (p < CAP) sbuf[p] = ((u64)f2s(d[k].y) << 32) | (u32)~(u32)(base4 + 1); }
        if (d[k].z >= T) { int p = atomicAdd(&scnt, 1); if (p < CAP) sbuf[p] = ((u64)f2s(d[k].z) << 32) | (u32)~(u32)(base4 + 2); }
        if (d[k].w >= T) { int p = atomicAdd(&scnt, 1); if (p < CAP) sbuf[p] = ((u64)f2s(d[k].w) << 32) | (u32)~(u32)(base4 + 3); }
    }
    if (extra >= T) { int p = atomicAdd(&scnt, 1); if (p < CAP) sbuf[p] = ((u64)f2s(extra) << 32) | (u32)~(u32)(VOCAB - 1); }
    __syncthreads();

    // ---- extraction: each wave sorts 128-entry region, wave 0 merges ----
    {
        u64 ka = sbuf[wave * 128 + lane];
        u64 kb = sbuf[wave * 128 + 64 + lane];
        u64 mine = 0;
#pragma unroll 1
        for (int it = 0; it < K; ++it) {
            u64 mm = wmax64(ka > kb ? ka : kb);
            if (lane == it) mine = mm;
            if (ka == mm) ka = 0; else if (kb == mm) kb = 0;
        }
        if (lane < K) wlist[wave * K + lane] = mine;
    }
    __syncthreads();

    if (tid < 64) {
        u64 cand = wlist[lane];
        u64 mine = 0;
#pragma unroll 1
        for (int it = 0; it < K; ++it) {
            u64 mm = wmax64(cand);
            if (lane == it) mine = mm;
            if (cand == mm) cand = 0;
        }
        if (lane < K) segk[((size_t)row * SPLIT + seg) * K + lane] = mine;
    }
}

// Phase 2: wave j merges row (b,j)'s 8x16 segment keys -> sorted row top-16
// (rank = extraction round); apply bias + sibling penalty; wave 0 selects the
// final top-16 of 128 with flattened-position tie-break.
__global__ __launch_bounds__(512) void merge_final(
    const u64* __restrict__ segk, const float* __restrict__ scores,
    const int* __restrict__ step_ptr, float* __restrict__ out)
{
    const int tid  = threadIdx.x;
    const int lane = tid & 63;
    const int j    = tid >> 6;       // beam 0..7
    const int b    = blockIdx.x;
    const int row  = b * BEAM + j;
    const int step = *step_ptr;

    __shared__ u64 rowkey[BEAM * K];
    __shared__ int rowvidx[BEAM * K];

    u64 ka = segk[(size_t)row * 128 + lane];
    u64 kb = segk[(size_t)row * 128 + 64 + lane];
    u64 mine = 0;
#pragma unroll 1
    for (int it = 0; it < K; ++it) {
        u64 mm = wmax64(ka > kb ? ka : kb);
        if (lane == it) mine = mm;
        if (ka == mm) ka = 0; else if (kb == mm) kb = 0;
    }

    float* out_s = out;
    float* out_i = out + BSZ * K;
    float* out_b = out + 2 * BSZ * K;

    if (step == 0) {
        // reference: top_k(lprobs[:,0,:]): idx%vocab=idx, idx//vocab=0
        if (j == 0 && lane < K) {
            out_s[b * K + lane] = s2f((u32)(mine >> 32));
            out_i[b * K + lane] = (float)(int)~(u32)mine;
            out_b[b * K + lane] = 0.0f;
        }
        return;
    }

    if (lane < K) {
        float v   = s2f((u32)(mine >> 32));
        float add = scores[row * NSTEP + step - 1];
        float sc  = v + add - (float)(lane + 1) * DIV_RATE;   // rank = lane
        int c = j * K + lane;
        rowkey[c]  = ((u64)f2s(sc) << 32) | (u32)(127 - c);   // lower c wins ties
        rowvidx[c] = (int)~(u32)mine;
    }
    __syncthreads();

    if (tid < 64) {
        u64 pa = rowkey[lane];
        u64 pb = rowkey[lane + 64];
        u64 m2 = 0;
#pragma unroll 1
        for (int it = 0; it < K; ++it) {
            u64 mm = wmax64(pa > pb ? pa : pb);
            if (lane == it) m2 = mm;
            if (pa == mm) pa = 0; else if (pb == mm) pb = 0;
        }
        if (lane < K) {
            int c = 127 - (int)(m2 & 0xFFFFFFFFull);
            out_s[b * K + lane] = s2f((u32)(m2 >> 32));
            out_i[b * K + lane] = (float)rowvidx[c];
            out_b[b * K + lane] = (float)(c >> 4);
        }
    }
}

extern "C" void kernel_launch(void* const* d_in, const int* in_sizes, int n_in,
                              void* d_out, int out_size, void* d_ws, size_t ws_size,
                              hipStream_t stream) {
    const float* lprobs = (const float*)d_in[0];
    const float* scores = (const float*)d_in[1];
    const int*   step   = (const int*)d_in[2];

    u64* segk = (u64*)d_ws;   // 512 rows * 8 segs * 16 keys * 8 B = 512 KB

    dim3 g1(SPLIT, BSZ * BEAM);
    topk_seg<<<g1, 256, 0, stream>>>(lprobs, segk);
    merge_final<<<BSZ, 512, 0, stream>>>(segk, scores, step, (float*)d_out);
}

// Round 3
// 174.631 us; speedup vs baseline: 1.8120x; 1.1317x over previous
//
#include <hip/hip_runtime.h>
#include <math.h>

// Problem constants: BSZ=64, BEAM=8, VOCAB=50257, STEP=5
#define BSZ   64
#define BEAM  8
#define VOCAB 50257
#define NSTEP 5
#define K     16
#define DIV_RATE 0.5f
#define SPLIT 8
#define N4    (VOCAB / 4)                  // 12564 float4s (+1 tail elem)
#define F4SEG ((N4 + SPLIT - 1) / SPLIT)   // 1571 float4 per segment
#define SEGCAP 512                         // per-seg LDS cap (proof bound 449)
#define ROWCAP_MAX 512                     // per-row global candidate cap

typedef unsigned long long u64;
typedef unsigned u32;

// order-preserving float<->uint (monotone for all non-NaN)
__device__ __forceinline__ u32 f2s(float f) {
    u32 u = __float_as_uint(f);
    return (u & 0x80000000u) ? ~u : (u | 0x80000000u);
}
__device__ __forceinline__ float s2f(u32 s) {
    u32 u = (s & 0x80000000u) ? (s ^ 0x80000000u) : ~s;
    return __uint_as_float(u);
}

// wave(64)-wide max of a u64 key
__device__ __forceinline__ u64 wmax64(u64 k) {
#pragma unroll
    for (int off = 32; off > 0; off >>= 1) {
        u32 lo = __shfl_xor((u32)k, off, 64);
        u32 hi = __shfl_xor((u32)(k >> 32), off, 64);
        u64 o = ((u64)hi << 32) | lo;
        if (o > k) k = o;
    }
    return k;
}

// full bitonic sort of one u32 per lane across the 64-lane wave, ASCENDING.
// 21 compare-exchange steps, each one u32 shuffle.
__device__ __forceinline__ u32 bitonic64_asc(u32 v, int lane) {
#define BSTEP(K_, J_)                                                        \
    {                                                                        \
        u32 o = __shfl_xor(v, (J_), 64);                                     \
        bool tmin = ((lane & (J_)) == 0) == ((lane & (K_)) == 0);            \
        v = tmin ? (v < o ? v : o) : (v > o ? v : o);                        \
    }
    BSTEP(2, 1)
    BSTEP(4, 2)  BSTEP(4, 1)
    BSTEP(8, 4)  BSTEP(8, 2)  BSTEP(8, 1)
    BSTEP(16, 8) BSTEP(16, 4) BSTEP(16, 2) BSTEP(16, 1)
    BSTEP(32, 16) BSTEP(32, 8) BSTEP(32, 4) BSTEP(32, 2) BSTEP(32, 1)
    BSTEP(64, 32) BSTEP(64, 16) BSTEP(64, 8) BSTEP(64, 4) BSTEP(64, 2) BSTEP(64, 1)
#undef BSTEP
    return v;
}

// Phase 1: per (row, segment) compute exact x16 = 16th largest of the 256
// per-thread maxima (subset property: x16 <= 16th largest element of the
// segment), then append all elements >= x16 (<= 449, expected ~16) to the
// row's global candidate buffer. No sorting/extraction of elements here.
__global__ __launch_bounds__(256) void collect(
    const float* __restrict__ lprobs, u64* __restrict__ rowbuf,
    int* __restrict__ rowcnt, int rowcap)
{
    const int tid  = threadIdx.x;
    const int lane = tid & 63;
    const int wave = tid >> 6;
    const int seg  = blockIdx.x;     // 0..7
    const int row  = blockIdx.y;     // 0..511

    const int s0 = seg * F4SEG;
    const int s1 = min(N4, s0 + F4SEG);
    const float4* rp4 = (const float4*)(lprobs + (size_t)row * VOCAB);

    // load segment into registers, per-thread max
    float4 d[7];
#pragma unroll
    for (int k = 0; k < 7; ++k) {
        int p = s0 + k * 256 + tid;
        if (p < s1) d[k] = rp4[p];
        else        d[k] = make_float4(-INFINITY, -INFINITY, -INFINITY, -INFINITY);
    }
    float extra = -INFINITY;                       // vocab tail element 50256
    if (seg == SPLIT - 1 && tid == 0) extra = ((const float*)rp4)[VOCAB - 1];

    float m = extra;
#pragma unroll
    for (int k = 0; k < 7; ++k)
        m = fmaxf(m, fmaxf(fmaxf(d[k].x, d[k].y), fmaxf(d[k].z, d[k].w)));

    __shared__ u32 smax[64];       // 4 waves x their top-16 maxima
    __shared__ u32 sthr;
    __shared__ int scnt, sbase;
    __shared__ u64 sbuf[SEGCAP];

    // per-wave bitonic sort of the 64 lane maxima (ascending);
    // lanes 48..63 hold the wave's top-16.
    u32 v = bitonic64_asc(f2s(m), lane);
    if (lane >= 48) smax[wave * 16 + (lane - 48)] = v;
    if (tid == 0) scnt = 0;
    __syncthreads();

    // wave 0: sort the 4x16 survivors; lane 48 = exact 16th largest of 256
    if (wave == 0) {
        u32 w = bitonic64_asc(smax[lane], lane);
        if (lane == 48) sthr = w;
    }
    __syncthreads();
    const float T = s2f(sthr);

    // dump candidates >= T into LDS (bound: <=16 threads own them, <=449 total)
#pragma unroll
    for (int k = 0; k < 7; ++k) {
        int base4 = 4 * (s0 + k * 256 + tid);
        if (d[k].x >= T) { int p = atomicAdd(&scnt, 1); if (p < SEGCAP) sbuf[p] = ((u64)f2s(d[k].x) << 32) | (u32)~(u32)(base4 + 0); }
        if (d[k].y >= T) { int p = atomicAdd(&scnt, 1); if (p < SEGCAP) sbuf[p] = ((u64)f2s(d[k].y) << 32) | (u32)~(u32)(base4 + 1); }
        if (d[k].z >= T) { int p = atomicAdd(&scnt, 1); if (p < SEGCAP) sbuf[p] = ((u64)f2s(d[k].z) << 32) | (u32)~(u32)(base4 + 2); }
        if (d[k].w >= T) { int p = atomicAdd(&scnt, 1); if (p < SEGCAP) sbuf[p] = ((u64)f2s(d[k].w) << 32) | (u32)~(u32)(base4 + 3); }
    }
    if (extra >= T) { int p = atomicAdd(&scnt, 1); if (p < SEGCAP) sbuf[p] = ((u64)f2s(extra) << 32) | (u32)~(u32)(VOCAB - 1); }
    __syncthreads();

    // append to the row's global candidate list
    int n = min(scnt, SEGCAP);
    if (tid == 0) sbase = atomicAdd(&rowcnt[row], n);
    __syncthreads();
    if (tid < n) {
        int g = sbase + tid;
        if (g < rowcap) rowbuf[(size_t)row * rowcap + g] = sbuf[tid];
    }
}

// Phase 2: block b (of 64), wave j: exact sorted top-16 of row (b,j)'s
// candidate list (16 rounds of reg-max + wave-argmax over <=1024 keys);
// then bias + sibling penalty; wave 0 selects the final top-16 of 128.
__global__ __launch_bounds__(512) void merge_final(
    const u64* __restrict__ rowbuf, const int* __restrict__ rowcnt,
    const float* __restrict__ scores, const int* __restrict__ step_ptr,
    float* __restrict__ out, int rowcap)
{
    const int tid  = threadIdx.x;
    const int lane = tid & 63;
    const int j    = tid >> 6;       // beam 0..7
    const int b    = blockIdx.x;
    const int row  = b * BEAM + j;
    const int step = *step_ptr;

    __shared__ u64 rowkey[BEAM * K];
    __shared__ int rowvidx[BEAM * K];

    const int n = min(rowcnt[row], rowcap);
    u64 k[8];
#pragma unroll
    for (int i = 0; i < 8; ++i) {
        int p = lane + 64 * i;
        k[i] = (p < n) ? rowbuf[(size_t)row * rowcap + p] : 0ull;
    }

    u64 mine = 0;
#pragma unroll 1
    for (int it = 0; it < K; ++it) {
        u64 lm = k[0];
#pragma unroll
        for (int i = 1; i < 8; ++i) lm = (k[i] > lm) ? k[i] : lm;
        u64 mm = wmax64(lm);
        if (lane == it) mine = mm;
#pragma unroll
        for (int i = 0; i < 8; ++i) if (k[i] == mm) k[i] = 0;
    }

    float* out_s = out;
    float* out_i = out + BSZ * K;
    float* out_b = out + 2 * BSZ * K;

    if (step == 0) {
        // reference: top_k(lprobs[:,0,:]): idx%vocab=idx, idx//vocab=0
        if (j == 0 && lane < K) {
            out_s[b * K + lane] = s2f((u32)(mine >> 32));
            out_i[b * K + lane] = (float)(int)~(u32)mine;
            out_b[b * K + lane] = 0.0f;
        }
        return;
    }

    if (lane < K) {
        float v   = s2f((u32)(mine >> 32));
        float add = scores[row * NSTEP + step - 1];
        float sc  = v + add - (float)(lane + 1) * DIV_RATE;   // rank = lane
        int c = j * K + lane;
        rowkey[c]  = ((u64)f2s(sc) << 32) | (u32)(127 - c);   // lower c wins ties
        rowvidx[c] = (int)~(u32)mine;
    }
    __syncthreads();

    if (tid < 64) {
        u64 pa = rowkey[lane];
        u64 pb = rowkey[lane + 64];
        u64 m2 = 0;
#pragma unroll 1
        for (int it = 0; it < K; ++it) {
            u64 mm = wmax64(pa > pb ? pa : pb);
            if (lane == it) m2 = mm;
            if (pa == mm) pa = 0; else if (pb == mm) pb = 0;
        }
        if (lane < K) {
            int c = 127 - (int)(m2 & 0xFFFFFFFFull);
            out_s[b * K + lane] = s2f((u32)(m2 >> 32));
            out_i[b * K + lane] = (float)rowvidx[c];
            out_b[b * K + lane] = (float)(c >> 4);
        }
    }
}

extern "C" void kernel_launch(void* const* d_in, const int* in_sizes, int n_in,
                              void* d_out, int out_size, void* d_ws, size_t ws_size,
                              hipStream_t stream) {
    const float* lprobs = (const float*)d_in[0];
    const float* scores = (const float*)d_in[1];
    const int*   step   = (const int*)d_in[2];

    // ws layout: [0,4KB) row counters (512 ints), then row candidate buffers
    int rowcap = ROWCAP_MAX;
    size_t need = 4096 + (size_t)BSZ * BEAM * rowcap * sizeof(u64);
    if (ws_size < need) {
        rowcap = (int)((ws_size - 4096) / ((size_t)BSZ * BEAM * sizeof(u64)));
    }
    int* rowcnt = (int*)d_ws;
    u64* rowbuf = (u64*)((char*)d_ws + 4096);

    hipMemsetAsync(d_ws, 0, 4096, stream);
    dim3 g1(SPLIT, BSZ * BEAM);
    collect<<<g1, 256, 0, stream>>>(lprobs, rowbuf, rowcnt, rowcap);
    merge_final<<<BSZ, 512, 0, stream>>>(rowbuf, rowcnt, scores, step,
                                         (float*)d_out, rowcap);
}